// Round 3
// baseline (560.416 us; speedup 1.0000x reference)
//
#include <hip/hip_runtime.h>
#include <hip/hip_bf16.h>

// Problem constants (B=2, L=512, Din=128, d=N=256, R=16, K=4)
#define kB   2
#define kL   512
#define kBL  1024
#define kDin 128
#define kD   256
#define kN   256
#define kR   16
#define kK   4

// ---------------------------------------------------------------------------
// On-device input-dtype detection. Read x's buffer as bf16: if the data is
// really bf16, even-indexed elements are genuine N(0,1) bf16 values (exponent
// ~[0x76,0x81]); if the data is f32, even bf16 slots are the low mantissa
// halves -> uniform random exponents. Count "insane" exponents over 64
// samples. Deterministic per input data -> graph-safe, same work every call.
// ---------------------------------------------------------------------------
__device__ __forceinline__ int inputs_are_f32(const void* x0) {
    const unsigned short* p = (const unsigned short*)x0;
    int insane = 0;
    #pragma unroll
    for (int j = 0; j < 64; j++) {
        unsigned short v = p[2 * j];
        int e = (v >> 7) & 0xFF;
        insane += ((e < 0x58 || e > 0x90) && e != 0) ? 1 : 0;
    }
    return insane >= 8;
}

// dual-dtype load of input tensor element i
__device__ __forceinline__ float ld(const void* p, int i, int f32) {
    return f32 ? ((const float*)p)[i]
               : __bfloat162float(((const __hip_bfloat16*)p)[i]);
}

__device__ __forceinline__ float silu_f(float v) {
    return v / (1.f + __expf(-v));
}

// ---------------------------------------------------------------------------
// 1. Transpose conv_w [o][i][k] (256 x 1024) -> wT [i*4+k][o] (1024 x 256)
// ---------------------------------------------------------------------------
__global__ void transpose_w(const void* __restrict__ src, float* __restrict__ wT,
                            const void* __restrict__ xraw) {
    int f32 = inputs_are_f32(xraw);
    __shared__ float tile[32][33];
    int c0 = blockIdx.x * 32;   // ik
    int r0 = blockIdx.y * 32;   // o
    int tx = threadIdx.x, ty = threadIdx.y;  // 32 x 8
    #pragma unroll
    for (int j = 0; j < 32; j += 8)
        tile[ty + j][tx] = ld(src, (r0 + ty + j) * 1024 + c0 + tx, f32);
    __syncthreads();
    #pragma unroll
    for (int j = 0; j < 32; j += 8)
        wT[(c0 + ty + j) * 256 + r0 + tx] = tile[tx][ty + j];
}

// ---------------------------------------------------------------------------
// 2. xi = x@W_in + b_in ; x_res = silu(x@W_res + b_res). 8 rows/block.
// ---------------------------------------------------------------------------
__global__ void __launch_bounds__(256) proj_in(
        const void* __restrict__ fx, const void* __restrict__ W_in,
        const void* __restrict__ b_in, const void* __restrict__ W_res,
        const void* __restrict__ b_res,
        float* __restrict__ xi, float* __restrict__ xres) {
    int f32 = inputs_are_f32(fx);
    __shared__ float xs[8][kDin];
    int bt0 = blockIdx.x * 8;
    int tid = threadIdx.x;
    for (int idx = tid; idx < 8 * kDin; idx += 256)
        xs[idx >> 7][idx & 127] = ld(fx, bt0 * kDin + idx, f32);
    __syncthreads();
    int o = tid;
    float ai[8] = {0,0,0,0,0,0,0,0}, ar[8] = {0,0,0,0,0,0,0,0};
    for (int i = 0; i < kDin; i++) {
        float wi = ld(W_in,  i * kD + o, f32);
        float wr = ld(W_res, i * kD + o, f32);
        #pragma unroll
        for (int r = 0; r < 8; r++) {
            ai[r] += xs[r][i] * wi;
            ar[r] += xs[r][i] * wr;
        }
    }
    float bi = ld(b_in, o, f32), br = ld(b_res, o, f32);
    #pragma unroll
    for (int r = 0; r < 8; r++) {
        xi[(bt0 + r) * kD + o] = ai[r] + bi;
        xres[(bt0 + r) * kD + o] = silu_f(ar[r] + br);
    }
}

// ---------------------------------------------------------------------------
// 3. u = silu(causal full conv1d(xi) + conv_b). 8 t-rows per block, one b.
//    c[b,t,o] = sum_{i,k} xi[b, t-3+k, i] * w[o,i,k]
// ---------------------------------------------------------------------------
__global__ void __launch_bounds__(256) conv_fwd(
        const float* __restrict__ xi, const float* __restrict__ wT,
        const void* __restrict__ conv_b, float* __restrict__ u,
        const void* __restrict__ xraw) {
    int f32 = inputs_are_f32(xraw);
    __shared__ float xs[11][kD];   // rows t0-3 .. t0+7
    int t0 = (blockIdx.x & 63) * 8;
    int b  = blockIdx.x >> 6;
    int tid = threadIdx.x;
    for (int idx = tid; idx < 11 * kD; idx += 256) {
        int j = idx >> 8, i = idx & 255;
        int t = t0 - 3 + j;
        xs[j][i] = (t >= 0) ? xi[(b * kL + t) * kD + i] : 0.f;
    }
    __syncthreads();
    int o = tid;
    float acc[8] = {0,0,0,0,0,0,0,0};
    for (int i = 0; i < kD; i++) {
        float a[11];
        #pragma unroll
        for (int j = 0; j < 11; j++) a[j] = xs[j][i];
        #pragma unroll
        for (int k = 0; k < kK; k++) {
            float w = wT[(i * 4 + k) * kD + o];
            #pragma unroll
            for (int r = 0; r < 8; r++) acc[r] += a[r + k] * w;
        }
    }
    float cb = ld(conv_b, o, f32);
    #pragma unroll
    for (int r = 0; r < 8; r++)
        u[(b * kL + t0 + r) * kD + o] = silu_f(acc[r] + cb);
}

// ---------------------------------------------------------------------------
// 4. t1 = u @ W_xdt  [BL x 16]
// ---------------------------------------------------------------------------
__global__ void __launch_bounds__(256) xdt_proj(
        const float* __restrict__ u, const void* __restrict__ W_xdt,
        float* __restrict__ t1, const void* __restrict__ xraw) {
    int f32 = inputs_are_f32(xraw);
    int bt = blockIdx.x * 16 + (threadIdx.x >> 4);
    int j = threadIdx.x & 15;
    const float* ur = u + bt * kD;
    float acc = 0.f;
    for (int i = 0; i < kD; i++) acc += ur[i] * ld(W_xdt, i * kR + j, f32);
    t1[bt * kR + j] = acc;
}

// ---------------------------------------------------------------------------
// 5. delta = softplus(t1@W_dt + b_dt); Bm = u@W_B; Cm = u@W_C. 8 rows/block.
// ---------------------------------------------------------------------------
__global__ void __launch_bounds__(256) proj_bcd(
        const float* __restrict__ u, const float* __restrict__ t1,
        const void* __restrict__ W_dt, const void* __restrict__ b_dt,
        const void* __restrict__ W_B, const void* __restrict__ W_C,
        float* __restrict__ delta, float* __restrict__ Bm, float* __restrict__ Cm,
        const void* __restrict__ xraw) {
    int f32 = inputs_are_f32(xraw);
    __shared__ float us[8][kD];
    __shared__ float ts[8][kR];
    int bt0 = blockIdx.x * 8;
    int tid = threadIdx.x;
    for (int idx = tid; idx < 8 * kD; idx += 256)
        us[idx >> 8][idx & 255] = u[bt0 * kD + idx];
    if (tid < 128) ts[tid >> 4][tid & 15] = t1[bt0 * kR + tid];
    __syncthreads();
    int o = tid;
    float ab[8] = {0,0,0,0,0,0,0,0}, ac[8] = {0,0,0,0,0,0,0,0};
    for (int i = 0; i < kD; i++) {
        float wb = ld(W_B, i * kN + o, f32);
        float wc = ld(W_C, i * kN + o, f32);
        #pragma unroll
        for (int r = 0; r < 8; r++) {
            ab[r] += us[r][i] * wb;
            ac[r] += us[r][i] * wc;
        }
    }
    float ad[8] = {0,0,0,0,0,0,0,0};
    #pragma unroll
    for (int j = 0; j < kR; j++) {
        float wd = ld(W_dt, j * kD + o, f32);
        #pragma unroll
        for (int r = 0; r < 8; r++) ad[r] += ts[r][j] * wd;
    }
    float bd = ld(b_dt, o, f32);
    #pragma unroll
    for (int r = 0; r < 8; r++) {
        Bm[(bt0 + r) * kN + o] = ab[r];
        Cm[(bt0 + r) * kN + o] = ac[r];
        float z = ad[r] + bd;
        delta[(bt0 + r) * kD + o] = (z > 20.f) ? z : log1pf(__expf(z));
    }
}

// ---------------------------------------------------------------------------
// 6. Selective scan. One wave per (b,d); lane owns n = lane*4 .. lane*4+3.
// ---------------------------------------------------------------------------
__global__ void __launch_bounds__(64) scan_kernel(
        const float* __restrict__ delta, const float* __restrict__ u,
        const float* __restrict__ Bm, const float* __restrict__ Cm,
        const void* __restrict__ A_log, float* __restrict__ ys,
        const void* __restrict__ xraw) {
    int f32 = inputs_are_f32(xraw);
    int d = blockIdx.x & 255;
    int b = blockIdx.x >> 8;
    int lane = threadIdx.x;

    float A0 = -__expf(ld(A_log, d * kN + 4 * lane + 0, f32));
    float A1 = -__expf(ld(A_log, d * kN + 4 * lane + 1, f32));
    float A2 = -__expf(ld(A_log, d * kN + 4 * lane + 2, f32));
    float A3 = -__expf(ld(A_log, d * kN + 4 * lane + 3, f32));

    const float*  dp = delta + b * kL * kD + d;
    const float*  up = u     + b * kL * kD + d;
    const float4* Bp = (const float4*)(Bm + b * kL * kN) + lane;
    const float4* Cp = (const float4*)(Cm + b * kL * kN) + lane;
    float* yp = ys + b * kL * kD + d;

    float h0 = 0, h1 = 0, h2 = 0, h3 = 0;
    float dt = dp[0], ut = up[0];
    float4 B4 = Bp[0], C4 = Cp[0];
    for (int t = 0; t < kL; t++) {
        float dtc = dt, utc = ut;
        float4 Bc = B4, Cc = C4;
        if (t < kL - 1) {
            dt = dp[(t + 1) * kD];
            ut = up[(t + 1) * kD];
            B4 = Bp[(t + 1) * (kN / 4)];
            C4 = Cp[(t + 1) * (kN / 4)];
        }
        float du = dtc * utc;
        h0 = __expf(dtc * A0) * h0 + du * Bc.x;
        h1 = __expf(dtc * A1) * h1 + du * Bc.y;
        h2 = __expf(dtc * A2) * h2 + du * Bc.z;
        h3 = __expf(dtc * A3) * h3 + du * Bc.w;
        float y = h0 * Cc.x + h1 * Cc.y + h2 * Cc.z + h3 * Cc.w;
        #pragma unroll
        for (int off = 32; off; off >>= 1) y += __shfl_xor(y, off, 64);
        if (lane == 0) yp[t * kD] = y;
    }
}

// ---------------------------------------------------------------------------
// 7. out = (ys + u*D + x_res) @ W_out + b_out. Store per detected dtype.
// ---------------------------------------------------------------------------
__global__ void __launch_bounds__(256) out_proj(
        const float* __restrict__ ys, const float* __restrict__ u,
        const void* __restrict__ Dv, const float* __restrict__ xres,
        const void* __restrict__ W_out, const void* __restrict__ b_out,
        void* __restrict__ out, const void* __restrict__ xraw) {
    int f32 = inputs_are_f32(xraw);
    __shared__ float vs[16][kD];
    int bt0 = blockIdx.x * 16;
    int tid = threadIdx.x;
    for (int idx = tid; idx < 16 * kD; idx += 256) {
        int g = bt0 * kD + idx;
        int i = idx & 255;
        vs[idx >> 8][i] = ys[g] + u[g] * ld(Dv, i, f32) + xres[g];
    }
    __syncthreads();
    int o = tid & 127;
    int rr = tid >> 7;   // 0..1
    float acc[8] = {0,0,0,0,0,0,0,0};
    for (int i = 0; i < kD; i++) {
        float w = ld(W_out, i * kDin + o, f32);
        #pragma unroll
        for (int r = 0; r < 8; r++) acc[r] += vs[rr + 2 * r][i] * w;
    }
    float bo = ld(b_out, o, f32);
    #pragma unroll
    for (int r = 0; r < 8; r++) {
        int gi = (bt0 + rr + 2 * r) * kDin + o;
        float v = acc[r] + bo;
        if (f32) ((float*)out)[gi] = v;
        else     ((__hip_bfloat16*)out)[gi] = __float2bfloat16(v);
    }
}

// ---------------------------------------------------------------------------
extern "C" void kernel_launch(void* const* d_in, const int* in_sizes, int n_in,
                              void* d_out, int out_size, void* d_ws, size_t ws_size,
                              hipStream_t stream) {
    const void* fx      = d_in[0];
    const void* fW_in   = d_in[1];
    const void* fb_in   = d_in[2];
    const void* fW_res  = d_in[3];
    const void* fb_res  = d_in[4];
    const void* fconv_w = d_in[5];
    const void* fconv_b = d_in[6];
    const void* fW_xdt  = d_in[7];
    const void* fW_dt   = d_in[8];
    const void* fb_dt   = d_in[9];
    const void* fW_B    = d_in[10];
    const void* fW_C    = d_in[11];
    const void* fA_log  = d_in[12];
    const void* fD      = d_in[13];
    const void* fW_out  = d_in[14];
    const void* fb_out  = d_in[15];

    // workspace: 6 x 262144 + 16384 floats = 6.06 MiB (aliased buffers)
    float* ws       = (float*)d_ws;
    float* xi_delta = ws;                 // xi, later delta
    float* xres     = ws + 1 * 262144;
    float* wT_Bmat  = ws + 2 * 262144;    // wT, later Bmat
    float* u        = ws + 3 * 262144;
    float* yss      = ws + 4 * 262144;
    float* Cmat     = ws + 5 * 262144;
    float* t1       = ws + 6 * 262144;    // 16384

    transpose_w<<<dim3(32, 8), dim3(32, 8), 0, stream>>>(fconv_w, wT_Bmat, fx);
    proj_in<<<kBL / 8, 256, 0, stream>>>(fx, fW_in, fb_in, fW_res, fb_res,
                                         xi_delta, xres);
    conv_fwd<<<kB * (kL / 8), 256, 0, stream>>>(xi_delta, wT_Bmat, fconv_b, u, fx);
    xdt_proj<<<kBL / 16, 256, 0, stream>>>(u, fW_xdt, t1, fx);
    proj_bcd<<<kBL / 8, 256, 0, stream>>>(u, t1, fW_dt, fb_dt, fW_B, fW_C,
                                          xi_delta, wT_Bmat, Cmat, fx);
    scan_kernel<<<kB * kD, 64, 0, stream>>>(xi_delta, u, wT_Bmat, Cmat, fA_log,
                                            yss, fx);
    out_proj<<<kBL / 16, 256, 0, stream>>>(yss, u, fD, xres, fW_out, fb_out,
                                           d_out, fx);
}

// Round 6
// 340.901 us; speedup vs baseline: 1.6439x; 1.6439x over previous
//
#include <hip/hip_runtime.h>
#include <hip/hip_bf16.h>

// Problem constants (B=2, L=512, Din=128, d=N=256, R=16, K=4)
#define kB   2
#define kL   512
#define kBL  1024
#define kDin 128
#define kD   256
#define kN   256
#define kR   16
#define kK   4
#define kS   8     // scan segments (= waves per block)
#define kT   64    // kL / kS

// ---------------------------------------------------------------------------
// On-device input-dtype detection (proven in R3; detector takes bf16 branch).
// ---------------------------------------------------------------------------
__device__ __forceinline__ int inputs_are_f32(const void* x0) {
    const unsigned short* p = (const unsigned short*)x0;
    int insane = 0;
    #pragma unroll
    for (int j = 0; j < 64; j++) {
        unsigned short v = p[2 * j];
        int e = (v >> 7) & 0xFF;
        insane += ((e < 0x58 || e > 0x90) && e != 0) ? 1 : 0;
    }
    return insane >= 8;
}

__device__ __forceinline__ float ld(const void* p, int i, int f32) {
    return f32 ? ((const float*)p)[i]
               : __bfloat162float(((const __hip_bfloat16*)p)[i]);
}

__device__ __forceinline__ float silu_f(float v) {
    return v / (1.f + __expf(-v));
}

// ---------------------------------------------------------------------------
// 1. Transpose conv_w [o][i][k] (256 x 1024) -> wT [i*4+k][o] (1024 x 256)
// ---------------------------------------------------------------------------
__global__ void transpose_w(const void* __restrict__ src, float* __restrict__ wT,
                            const void* __restrict__ xraw) {
    int f32 = inputs_are_f32(xraw);
    __shared__ float tile[32][33];
    int c0 = blockIdx.x * 32;   // ik
    int r0 = blockIdx.y * 32;   // o
    int tx = threadIdx.x, ty = threadIdx.y;  // 32 x 8
    #pragma unroll
    for (int j = 0; j < 32; j += 8)
        tile[ty + j][tx] = ld(src, (r0 + ty + j) * 1024 + c0 + tx, f32);
    __syncthreads();
    #pragma unroll
    for (int j = 0; j < 32; j += 8)
        wT[(c0 + ty + j) * 256 + r0 + tx] = tile[tx][ty + j];
}

// ---------------------------------------------------------------------------
// 2. xi = x@W_in + b_in ; x_res = silu(x@W_res + b_res). 8 rows/block.
// ---------------------------------------------------------------------------
__global__ void __launch_bounds__(256) proj_in(
        const void* __restrict__ fx, const void* __restrict__ W_in,
        const void* __restrict__ b_in, const void* __restrict__ W_res,
        const void* __restrict__ b_res,
        float* __restrict__ xi, float* __restrict__ xres) {
    int f32 = inputs_are_f32(fx);
    __shared__ float xs[8][kDin];
    int bt0 = blockIdx.x * 8;
    int tid = threadIdx.x;
    for (int idx = tid; idx < 8 * kDin; idx += 256)
        xs[idx >> 7][idx & 127] = ld(fx, bt0 * kDin + idx, f32);
    __syncthreads();
    int o = tid;
    float ai[8] = {0,0,0,0,0,0,0,0}, ar[8] = {0,0,0,0,0,0,0,0};
    for (int i = 0; i < kDin; i++) {
        float wi = ld(W_in,  i * kD + o, f32);
        float wr = ld(W_res, i * kD + o, f32);
        #pragma unroll
        for (int r = 0; r < 8; r++) {
            ai[r] += xs[r][i] * wi;
            ar[r] += xs[r][i] * wr;
        }
    }
    float bi = ld(b_in, o, f32), br = ld(b_res, o, f32);
    #pragma unroll
    for (int r = 0; r < 8; r++) {
        xi[(bt0 + r) * kD + o] = ai[r] + bi;
        xres[(bt0 + r) * kD + o] = silu_f(ar[r] + br);
    }
}

// ---------------------------------------------------------------------------
// 3. u = silu(causal full conv1d(xi) + conv_b). 8 t-rows per block, one b.
// ---------------------------------------------------------------------------
__global__ void __launch_bounds__(256) conv_fwd(
        const float* __restrict__ xi, const float* __restrict__ wT,
        const void* __restrict__ conv_b, float* __restrict__ u,
        const void* __restrict__ xraw) {
    int f32 = inputs_are_f32(xraw);
    __shared__ float xs[11][kD];   // rows t0-3 .. t0+7
    int t0 = (blockIdx.x & 63) * 8;
    int b  = blockIdx.x >> 6;
    int tid = threadIdx.x;
    for (int idx = tid; idx < 11 * kD; idx += 256) {
        int j = idx >> 8, i = idx & 255;
        int t = t0 - 3 + j;
        xs[j][i] = (t >= 0) ? xi[(b * kL + t) * kD + i] : 0.f;
    }
    __syncthreads();
    int o = tid;
    float acc[8] = {0,0,0,0,0,0,0,0};
    for (int i = 0; i < kD; i++) {
        float a[11];
        #pragma unroll
        for (int j = 0; j < 11; j++) a[j] = xs[j][i];
        #pragma unroll
        for (int k = 0; k < kK; k++) {
            float w = wT[(i * 4 + k) * kD + o];
            #pragma unroll
            for (int r = 0; r < 8; r++) acc[r] += a[r + k] * w;
        }
    }
    float cb = ld(conv_b, o, f32);
    #pragma unroll
    for (int r = 0; r < 8; r++)
        u[(b * kL + t0 + r) * kD + o] = silu_f(acc[r] + cb);
}

// ---------------------------------------------------------------------------
// 4. t1 = u @ W_xdt  [BL x 16]
// ---------------------------------------------------------------------------
__global__ void __launch_bounds__(256) xdt_proj(
        const float* __restrict__ u, const void* __restrict__ W_xdt,
        float* __restrict__ t1, const void* __restrict__ xraw) {
    int f32 = inputs_are_f32(xraw);
    int bt = blockIdx.x * 16 + (threadIdx.x >> 4);
    int j = threadIdx.x & 15;
    const float* ur = u + bt * kD;
    float acc = 0.f;
    for (int i = 0; i < kD; i++) acc += ur[i] * ld(W_xdt, i * kR + j, f32);
    t1[bt * kR + j] = acc;
}

// ---------------------------------------------------------------------------
// 5. delta = softplus(t1@W_dt + b_dt); Bm = u@W_B; Cm = u@W_C. 8 rows/block.
// ---------------------------------------------------------------------------
__global__ void __launch_bounds__(256) proj_bcd(
        const float* __restrict__ u, const float* __restrict__ t1,
        const void* __restrict__ W_dt, const void* __restrict__ b_dt,
        const void* __restrict__ W_B, const void* __restrict__ W_C,
        float* __restrict__ delta, float* __restrict__ Bm, float* __restrict__ Cm,
        const void* __restrict__ xraw) {
    int f32 = inputs_are_f32(xraw);
    __shared__ float us[8][kD];
    __shared__ float ts[8][kR];
    int bt0 = blockIdx.x * 8;
    int tid = threadIdx.x;
    for (int idx = tid; idx < 8 * kD; idx += 256)
        us[idx >> 8][idx & 255] = u[bt0 * kD + idx];
    if (tid < 128) ts[tid >> 4][tid & 15] = t1[bt0 * kR + tid];
    __syncthreads();
    int o = tid;
    float ab[8] = {0,0,0,0,0,0,0,0}, ac[8] = {0,0,0,0,0,0,0,0};
    for (int i = 0; i < kD; i++) {
        float wb = ld(W_B, i * kN + o, f32);
        float wc = ld(W_C, i * kN + o, f32);
        #pragma unroll
        for (int r = 0; r < 8; r++) {
            ab[r] += us[r][i] * wb;
            ac[r] += us[r][i] * wc;
        }
    }
    float ad[8] = {0,0,0,0,0,0,0,0};
    #pragma unroll
    for (int j = 0; j < kR; j++) {
        float wd = ld(W_dt, j * kD + o, f32);
        #pragma unroll
        for (int r = 0; r < 8; r++) ad[r] += ts[r][j] * wd;
    }
    float bd = ld(b_dt, o, f32);
    #pragma unroll
    for (int r = 0; r < 8; r++) {
        Bm[(bt0 + r) * kN + o] = ab[r];
        Cm[(bt0 + r) * kN + o] = ac[r];
        float z = ad[r] + bd;
        delta[(bt0 + r) * kD + o] = (z > 20.f) ? z : log1pf(__expf(z));
    }
}

// ---------------------------------------------------------------------------
// 6. NEW (the only change vs R3): fused segmented selective scan.
//    Block = (b,d), 8 waves = 8 segments of 64 t. Lane owns n=4*lane..+3,
//    and (for dt/u) t = s*64+lane. Pass 1: segment-local h (h0=0) + dsum
//    -> LDS. Barrier. Combine h_init via telescoped exp(A*sum dt). Pass 2:
//    rescan, y -> yss (pure store; D*u and xres added in out_proj, as R3).
// ---------------------------------------------------------------------------
__global__ void __launch_bounds__(512) scan_fused(
        const float* __restrict__ delta, const float* __restrict__ u,
        const float* __restrict__ Bm, const float* __restrict__ Cm,
        const void* __restrict__ A_log, float* __restrict__ ys,
        const void* __restrict__ xraw) {
    int f32 = inputs_are_f32(xraw);
    __shared__ float hpart[kS][kN];
    __shared__ float dsumS[kS];
    int d = blockIdx.x & 255;
    int b = blockIdx.x >> 8;
    int s    = threadIdx.x >> 6;
    int lane = threadIdx.x & 63;

    float A0 = -__expf(ld(A_log, d * kN + 4 * lane + 0, f32));
    float A1 = -__expf(ld(A_log, d * kN + 4 * lane + 1, f32));
    float A2 = -__expf(ld(A_log, d * kN + 4 * lane + 2, f32));
    float A3 = -__expf(ld(A_log, d * kN + 4 * lane + 3, f32));

    // this lane's own t (for dt/u): t_global = s*64 + lane
    int gtu = (b * kL + s * kT + lane) * kD + d;
    float my_dt = delta[gtu];
    float my_u  = u[gtu];
    float my_du = my_dt * my_u;

    // wave-sum of my_dt = segment dsum
    float dsum = my_dt;
    #pragma unroll
    for (int off = 32; off; off >>= 1) dsum += __shfl_xor(dsum, off, 64);

    const float4* Bp = (const float4*)(Bm + (b * kL + s * kT) * kN) + lane;
    const float4* Cp = (const float4*)(Cm + (b * kL + s * kT) * kN) + lane;

    // pass 1: segment-local scan from h=0
    float h0 = 0, h1 = 0, h2 = 0, h3 = 0;
    for (int t = 0; t < kT; t++) {
        float dt = __shfl(my_dt, t, 64);
        float du = __shfl(my_du, t, 64);
        float4 B4 = Bp[t * (kN / 4)];
        h0 = __expf(dt * A0) * h0 + du * B4.x;
        h1 = __expf(dt * A1) * h1 + du * B4.y;
        h2 = __expf(dt * A2) * h2 + du * B4.z;
        h3 = __expf(dt * A3) * h3 + du * B4.w;
    }
    hpart[s][4 * lane + 0] = h0;
    hpart[s][4 * lane + 1] = h1;
    hpart[s][4 * lane + 2] = h2;
    hpart[s][4 * lane + 3] = h3;
    if (lane == 0) dsumS[s] = dsum;
    __syncthreads();

    // combine prior segments: h_init = sum_{j<s} exp(A*P_j) * hpart[j],
    // P_j = sum_{m=j+1}^{s-1} dsum_m (telescoped segment decay)
    h0 = h1 = h2 = h3 = 0;
    float P = 0.f;
    for (int j = s - 1; j >= 0; j--) {
        h0 += __expf(A0 * P) * hpart[j][4 * lane + 0];
        h1 += __expf(A1 * P) * hpart[j][4 * lane + 1];
        h2 += __expf(A2 * P) * hpart[j][4 * lane + 2];
        h3 += __expf(A3 * P) * hpart[j][4 * lane + 3];
        P += dsumS[j];
    }

    // pass 2: rescan with correct h_init; y = h.C
    float* yp = ys + (b * kL + s * kT) * kD + d;
    for (int t = 0; t < kT; t++) {
        float dt = __shfl(my_dt, t, 64);
        float du = __shfl(my_du, t, 64);
        float4 B4 = Bp[t * (kN / 4)];
        float4 C4 = Cp[t * (kN / 4)];
        h0 = __expf(dt * A0) * h0 + du * B4.x;
        h1 = __expf(dt * A1) * h1 + du * B4.y;
        h2 = __expf(dt * A2) * h2 + du * B4.z;
        h3 = __expf(dt * A3) * h3 + du * B4.w;
        float y = h0 * C4.x + h1 * C4.y + h2 * C4.z + h3 * C4.w;
        #pragma unroll
        for (int off = 32; off; off >>= 1) y += __shfl_xor(y, off, 64);
        if (lane == 0) yp[t * kD] = y;
    }
}

// ---------------------------------------------------------------------------
// 7. out = (ys + u*D + x_res) @ W_out + b_out. Store per detected dtype.
// ---------------------------------------------------------------------------
__global__ void __launch_bounds__(256) out_proj(
        const float* __restrict__ ys, const float* __restrict__ u,
        const void* __restrict__ Dv, const float* __restrict__ xres,
        const void* __restrict__ W_out, const void* __restrict__ b_out,
        void* __restrict__ out, const void* __restrict__ xraw) {
    int f32 = inputs_are_f32(xraw);
    __shared__ float vs[16][kD];
    int bt0 = blockIdx.x * 16;
    int tid = threadIdx.x;
    for (int idx = tid; idx < 16 * kD; idx += 256) {
        int g = bt0 * kD + idx;
        int i = idx & 255;
        vs[idx >> 8][i] = ys[g] + u[g] * ld(Dv, i, f32) + xres[g];
    }
    __syncthreads();
    int o = tid & 127;
    int rr = tid >> 7;   // 0..1
    float acc[8] = {0,0,0,0,0,0,0,0};
    for (int i = 0; i < kD; i++) {
        float w = ld(W_out, i * kDin + o, f32);
        #pragma unroll
        for (int r = 0; r < 8; r++) acc[r] += vs[rr + 2 * r][i] * w;
    }
    float bo = ld(b_out, o, f32);
    #pragma unroll
    for (int r = 0; r < 8; r++) {
        int gi = (bt0 + rr + 2 * r) * kDin + o;
        float v = acc[r] + bo;
        if (f32) ((float*)out)[gi] = v;
        else     ((__hip_bfloat16*)out)[gi] = __float2bfloat16(v);
    }
}

// ---------------------------------------------------------------------------
extern "C" void kernel_launch(void* const* d_in, const int* in_sizes, int n_in,
                              void* d_out, int out_size, void* d_ws, size_t ws_size,
                              hipStream_t stream) {
    const void* fx      = d_in[0];
    const void* fW_in   = d_in[1];
    const void* fb_in   = d_in[2];
    const void* fW_res  = d_in[3];
    const void* fb_res  = d_in[4];
    const void* fconv_w = d_in[5];
    const void* fconv_b = d_in[6];
    const void* fW_xdt  = d_in[7];
    const void* fW_dt   = d_in[8];
    const void* fb_dt   = d_in[9];
    const void* fW_B    = d_in[10];
    const void* fW_C    = d_in[11];
    const void* fA_log  = d_in[12];
    const void* fD      = d_in[13];
    const void* fW_out  = d_in[14];
    const void* fb_out  = d_in[15];

    // workspace: 6 x 262144 + 16384 floats = 6.06 MiB (R3-proven layout)
    float* ws       = (float*)d_ws;
    float* xi_delta = ws;                 // xi, later delta
    float* xres     = ws + 1 * 262144;
    float* wT_Bmat  = ws + 2 * 262144;    // wT, later Bmat
    float* u        = ws + 3 * 262144;
    float* yss      = ws + 4 * 262144;
    float* Cmat     = ws + 5 * 262144;
    float* t1       = ws + 6 * 262144;    // 16384

    transpose_w<<<dim3(32, 8), dim3(32, 8), 0, stream>>>(fconv_w, wT_Bmat, fx);
    proj_in<<<kBL / 8, 256, 0, stream>>>(fx, fW_in, fb_in, fW_res, fb_res,
                                         xi_delta, xres);
    conv_fwd<<<kB * (kL / 8), 256, 0, stream>>>(xi_delta, wT_Bmat, fconv_b, u, fx);
    xdt_proj<<<kBL / 16, 256, 0, stream>>>(u, fW_xdt, t1, fx);
    proj_bcd<<<kBL / 8, 256, 0, stream>>>(u, t1, fW_dt, fb_dt, fW_B, fW_C,
                                          xi_delta, wT_Bmat, Cmat, fx);
    scan_fused<<<kB * kD, 512, 0, stream>>>(xi_delta, u, wT_Bmat, Cmat, fA_log,
                                            yss, fx);
    out_proj<<<kBL / 16, 256, 0, stream>>>(yss, u, fD, xres, fW_out, fb_out,
                                           d_out, fx);
}

// Round 7
// 181.710 us; speedup vs baseline: 3.0841x; 1.8761x over previous
//
#include <hip/hip_runtime.h>
#include <hip/hip_bf16.h>

// Problem constants (B=2, L=512, Din=128, d=N=256, R=16, K=4)
// Established facts: inputs f32, output f32, ws budget <= ~6.1 MiB.
#define kB   2
#define kL   512
#define kBL  1024
#define kDin 128
#define kD   256
#define kN   256
#define kR   16
#define kK   4
#define kS   8     // scan segments (= waves per block)
#define kT   64    // kL / kS

__device__ __forceinline__ float silu_f(float v) { return v / (1.f + __expf(-v)); }
__device__ __forceinline__ float softplus_f(float z) {
    return (z > 20.f) ? z : log1pf(__expf(z));
}
__device__ __forceinline__ float4 f4fma(float s, float4 w, float4 a) {
    a.x += s * w.x; a.y += s * w.y; a.z += s * w.z; a.w += s * w.w; return a;
}

// ---------------------------------------------------------------------------
// K1: blocks [0,256) transpose conv_w [o][ik] -> wT [ik][o];
//     blocks [256,768) proj_in: xi = x@W_in+b_in, xres = silu(x@W_res+b_res),
//     2 rows/block; threads = 64 q (4 outs, float4) x 2 mat x 2 K-split.
// ---------------------------------------------------------------------------
__global__ void __launch_bounds__(256) pre_kernel(
        const float* __restrict__ x, const float* __restrict__ W_in,
        const float* __restrict__ b_in, const float* __restrict__ W_res,
        const float* __restrict__ b_res, const float* __restrict__ conv_w,
        float* __restrict__ wT, float* __restrict__ xi, float* __restrict__ xres) {
    __shared__ float tile[32][33];
    __shared__ float xs[2][kDin];
    __shared__ float red[128][9];
    int bid = blockIdx.x, tid = threadIdx.x;
    if (bid < 256) {
        int c0 = (bid & 31) * 32, r0 = (bid >> 5) * 32;
        int tx = tid & 31, ty = tid >> 5;
        #pragma unroll
        for (int j = 0; j < 32; j += 8)
            tile[ty + j][tx] = conv_w[(r0 + ty + j) * 1024 + c0 + tx];
        __syncthreads();
        #pragma unroll
        for (int j = 0; j < 32; j += 8)
            wT[(c0 + ty + j) * 256 + r0 + tx] = tile[tx][ty + j];
        return;
    }
    int bt0 = (bid - 256) * 2;
    xs[tid >> 7][tid & 127] = x[bt0 * kDin + tid];
    __syncthreads();
    int q = tid & 63, m = (tid >> 6) & 1, ks = tid >> 7;
    const float* W = m ? W_res : W_in;
    float4 a0 = {0,0,0,0}, a1 = {0,0,0,0};
    int i0 = ks * 64;
    #pragma unroll 4
    for (int i = i0; i < i0 + 64; i++) {
        float4 w = ((const float4*)(W + i * kD))[q];
        a0 = f4fma(xs[0][i], w, a0);
        a1 = f4fma(xs[1][i], w, a1);
    }
    if (ks) {
        float* rr = red[tid - 128];
        rr[0] = a0.x; rr[1] = a0.y; rr[2] = a0.z; rr[3] = a0.w;
        rr[4] = a1.x; rr[5] = a1.y; rr[6] = a1.z; rr[7] = a1.w;
    }
    __syncthreads();
    if (!ks) {
        const float* rr = red[tid];
        a0.x += rr[0]; a0.y += rr[1]; a0.z += rr[2]; a0.w += rr[3];
        a1.x += rr[4]; a1.y += rr[5]; a1.z += rr[6]; a1.w += rr[7];
        float4 bv = ((const float4*)(m ? b_res : b_in))[q];
        a0.x += bv.x; a0.y += bv.y; a0.z += bv.z; a0.w += bv.w;
        a1.x += bv.x; a1.y += bv.y; a1.z += bv.z; a1.w += bv.w;
        if (m) {
            float4 s0 = {silu_f(a0.x), silu_f(a0.y), silu_f(a0.z), silu_f(a0.w)};
            float4 s1 = {silu_f(a1.x), silu_f(a1.y), silu_f(a1.z), silu_f(a1.w)};
            ((float4*)(xres + (bt0 + 0) * kD))[q] = s0;
            ((float4*)(xres + (bt0 + 1) * kD))[q] = s1;
        } else {
            ((float4*)(xi + (bt0 + 0) * kD))[q] = a0;
            ((float4*)(xi + (bt0 + 1) * kD))[q] = a1;
        }
    }
}

// ---------------------------------------------------------------------------
// K2: u = silu(causal conv1d(xi) + conv_b). 4 rows/block, 512 thr =
//     64 q (4 outs, float4) x 8 K-split (128 ik each). LDS reduce.
// ---------------------------------------------------------------------------
__global__ void __launch_bounds__(512) conv_fwd(
        const float* __restrict__ xi, const float* __restrict__ wT,
        const float* __restrict__ conv_b, float* __restrict__ u) {
    __shared__ float xs[7][kD];          // rows t0-3 .. t0+3
    __shared__ float red[7][64][17];
    int bid = blockIdx.x, tid = threadIdx.x;
    int b = bid >> 7, t0 = (bid & 127) * 4;
    for (int idx = tid; idx < 7 * kD; idx += 512) {
        int j = idx >> 8, i = idx & 255;
        int t = t0 - 3 + j;
        xs[j][i] = (t >= 0) ? xi[(b * kL + t) * kD + i] : 0.f;
    }
    __syncthreads();
    int q = tid & 63, ks = tid >> 6;
    float4 a[4] = {{0,0,0,0},{0,0,0,0},{0,0,0,0},{0,0,0,0}};
    int ik0 = ks * 128;
    #pragma unroll 4
    for (int ik = ik0; ik < ik0 + 128; ik++) {
        float4 w = ((const float4*)(wT + ik * kD))[q];
        int ii = ik >> 2, k = ik & 3;
        #pragma unroll
        for (int r = 0; r < 4; r++) a[r] = f4fma(xs[k + r][ii], w, a[r]);
    }
    if (ks) {
        float* rr = red[ks - 1][q];
        #pragma unroll
        for (int r = 0; r < 4; r++) {
            rr[4*r+0] = a[r].x; rr[4*r+1] = a[r].y;
            rr[4*r+2] = a[r].z; rr[4*r+3] = a[r].w;
        }
    }
    __syncthreads();
    if (!ks) {
        #pragma unroll
        for (int p = 0; p < 7; p++) {
            const float* rr = red[p][q];
            #pragma unroll
            for (int r = 0; r < 4; r++) {
                a[r].x += rr[4*r+0]; a[r].y += rr[4*r+1];
                a[r].z += rr[4*r+2]; a[r].w += rr[4*r+3];
            }
        }
        float4 cb = ((const float4*)conv_b)[q];
        #pragma unroll
        for (int r = 0; r < 4; r++) {
            float4 v = {silu_f(a[r].x + cb.x), silu_f(a[r].y + cb.y),
                        silu_f(a[r].z + cb.z), silu_f(a[r].w + cb.w)};
            ((float4*)(u + (b * kL + t0 + r) * kD))[q] = v;
        }
    }
}

// ---------------------------------------------------------------------------
// K3: fused xdt + bcd. 2 rows/block, 512 blocks.
//     t1 = u@W_xdt (128 thr, K-quarters); delta = softplus(t1@W_dt + b_dt);
//     Bm = u@W_B; Cm = u@W_C (64 q x 2 mat x 2 K-split, float4).
// ---------------------------------------------------------------------------
__global__ void __launch_bounds__(256) proj_bcd(
        const float* __restrict__ u, const float* __restrict__ W_xdt,
        const float* __restrict__ W_dt, const float* __restrict__ b_dt,
        const float* __restrict__ W_B, const float* __restrict__ W_C,
        float* __restrict__ delta, float* __restrict__ Bm, float* __restrict__ Cm) {
    __shared__ float us[2][kD];
    __shared__ float tpart[128];
    __shared__ float ts[2][kR];
    __shared__ float red[128][9];
    int bt0 = blockIdx.x * 2, tid = threadIdx.x;
    us[0][tid] = u[(bt0 + 0) * kD + tid];
    us[1][tid] = u[(bt0 + 1) * kD + tid];
    __syncthreads();
    if (tid < 128) {     // t1 partials: r x 16 j x 4 K-quarters
        int r = tid >> 6, j = (tid >> 2) & 15, kq = tid & 3;
        float acc = 0.f;
        #pragma unroll 4
        for (int i = kq * 64; i < kq * 64 + 64; i++)
            acc += us[r][i] * W_xdt[i * kR + j];
        tpart[tid] = acc;
    }
    __syncthreads();
    if (tid < 32) {
        int r = tid >> 4, j = tid & 15;
        int base = r * 64 + j * 4;
        ts[r][j] = tpart[base] + tpart[base+1] + tpart[base+2] + tpart[base+3];
    }
    __syncthreads();
    int q = tid & 63, m = (tid >> 6) & 1, ks = tid >> 7;
    const float* W = m ? W_C : W_B;
    float4 a0 = {0,0,0,0}, a1 = {0,0,0,0};
    int i0 = ks * 128;
    #pragma unroll 4
    for (int i = i0; i < i0 + 128; i++) {
        float4 w = ((const float4*)(W + i * kN))[q];
        a0 = f4fma(us[0][i], w, a0);
        a1 = f4fma(us[1][i], w, a1);
    }
    if (ks) {
        float* rr = red[tid - 128];
        rr[0] = a0.x; rr[1] = a0.y; rr[2] = a0.z; rr[3] = a0.w;
        rr[4] = a1.x; rr[5] = a1.y; rr[6] = a1.z; rr[7] = a1.w;
    }
    __syncthreads();
    if (!ks) {
        const float* rr = red[tid];
        a0.x += rr[0]; a0.y += rr[1]; a0.z += rr[2]; a0.w += rr[3];
        a1.x += rr[4]; a1.y += rr[5]; a1.z += rr[6]; a1.w += rr[7];
        float* O = m ? Cm : Bm;
        ((float4*)(O + (bt0 + 0) * kN))[q] = a0;
        ((float4*)(O + (bt0 + 1) * kN))[q] = a1;
    }
    if (tid < 64) {      // delta: 16-j dot, float4 outs
        float4 d0 = {0,0,0,0}, d1 = {0,0,0,0};
        #pragma unroll
        for (int j = 0; j < kR; j++) {
            float4 w = ((const float4*)(W_dt + j * kD))[tid];
            d0 = f4fma(ts[0][j], w, d0);
            d1 = f4fma(ts[1][j], w, d1);
        }
        float4 bd = ((const float4*)b_dt)[tid];
        float4 o0 = {softplus_f(d0.x + bd.x), softplus_f(d0.y + bd.y),
                     softplus_f(d0.z + bd.z), softplus_f(d0.w + bd.w)};
        float4 o1 = {softplus_f(d1.x + bd.x), softplus_f(d1.y + bd.y),
                     softplus_f(d1.z + bd.z), softplus_f(d1.w + bd.w)};
        ((float4*)(delta + (bt0 + 0) * kD))[tid] = o0;
        ((float4*)(delta + (bt0 + 1) * kD))[tid] = o1;
    }
}

// ---------------------------------------------------------------------------
// K4: fused segmented selective scan (R6-proven). Block = (b,d), 8 waves =
//     8 segments of 64 t; LDS h_part/dsum exchange; telescoped combine.
// ---------------------------------------------------------------------------
__global__ void __launch_bounds__(512) scan_fused(
        const float* __restrict__ delta, const float* __restrict__ u,
        const float* __restrict__ Bm, const float* __restrict__ Cm,
        const float* __restrict__ A_log, float* __restrict__ ys) {
    __shared__ float hpart[kS][kN];
    __shared__ float dsumS[kS];
    int d = blockIdx.x & 255;
    int b = blockIdx.x >> 8;
    int s    = threadIdx.x >> 6;
    int lane = threadIdx.x & 63;

    float4 al = ((const float4*)(A_log + d * kN))[lane];
    float A0 = -__expf(al.x), A1 = -__expf(al.y);
    float A2 = -__expf(al.z), A3 = -__expf(al.w);

    int gtu = (b * kL + s * kT + lane) * kD + d;
    float my_dt = delta[gtu];
    float my_u  = u[gtu];
    float my_du = my_dt * my_u;

    float dsum = my_dt;
    #pragma unroll
    for (int off = 32; off; off >>= 1) dsum += __shfl_xor(dsum, off, 64);

    const float4* Bp = (const float4*)(Bm + (b * kL + s * kT) * kN) + lane;
    const float4* Cp = (const float4*)(Cm + (b * kL + s * kT) * kN) + lane;

    float h0 = 0, h1 = 0, h2 = 0, h3 = 0;
    for (int t = 0; t < kT; t++) {
        float dt = __shfl(my_dt, t, 64);
        float du = __shfl(my_du, t, 64);
        float4 B4 = Bp[t * (kN / 4)];
        h0 = __expf(dt * A0) * h0 + du * B4.x;
        h1 = __expf(dt * A1) * h1 + du * B4.y;
        h2 = __expf(dt * A2) * h2 + du * B4.z;
        h3 = __expf(dt * A3) * h3 + du * B4.w;
    }
    hpart[s][4 * lane + 0] = h0;
    hpart[s][4 * lane + 1] = h1;
    hpart[s][4 * lane + 2] = h2;
    hpart[s][4 * lane + 3] = h3;
    if (lane == 0) dsumS[s] = dsum;
    __syncthreads();

    h0 = h1 = h2 = h3 = 0;
    float P = 0.f;
    for (int j = s - 1; j >= 0; j--) {
        h0 += __expf(A0 * P) * hpart[j][4 * lane + 0];
        h1 += __expf(A1 * P) * hpart[j][4 * lane + 1];
        h2 += __expf(A2 * P) * hpart[j][4 * lane + 2];
        h3 += __expf(A3 * P) * hpart[j][4 * lane + 3];
        P += dsumS[j];
    }

    float* yp = ys + (b * kL + s * kT) * kD + d;
    for (int t = 0; t < kT; t++) {
        float dt = __shfl(my_dt, t, 64);
        float du = __shfl(my_du, t, 64);
        float4 B4 = Bp[t * (kN / 4)];
        float4 C4 = Cp[t * (kN / 4)];
        h0 = __expf(dt * A0) * h0 + du * B4.x;
        h1 = __expf(dt * A1) * h1 + du * B4.y;
        h2 = __expf(dt * A2) * h2 + du * B4.z;
        h3 = __expf(dt * A3) * h3 + du * B4.w;
        float y = h0 * C4.x + h1 * C4.y + h2 * C4.z + h3 * C4.w;
        #pragma unroll
        for (int off = 32; off; off >>= 1) y += __shfl_xor(y, off, 64);
        if (lane == 0) yp[t * kD] = y;
    }
}

// ---------------------------------------------------------------------------
// K5: out = (ys + u*D + xres) @ W_out + b_out -> f32. 2 rows/block,
//     512 blocks; 32 q (4 outs, float4) x 8 K-split (32 i each).
// ---------------------------------------------------------------------------
__global__ void __launch_bounds__(256) out_proj(
        const float* __restrict__ ys, const float* __restrict__ u,
        const float* __restrict__ Dv, const float* __restrict__ xres,
        const float* __restrict__ W_out, const float* __restrict__ b_out,
        float* __restrict__ out) {
    __shared__ float vs[2][kD];
    __shared__ float red[224][9];
    int bt0 = blockIdx.x * 2, tid = threadIdx.x;
    for (int idx = tid; idx < 512; idx += 256) {
        int r = idx >> 8, i = idx & 255;
        int g = (bt0 + r) * kD + i;
        vs[r][i] = ys[g] + u[g] * Dv[i] + xres[g];
    }
    __syncthreads();
    int q = tid & 31, ks = tid >> 5;
    float4 a0 = {0,0,0,0}, a1 = {0,0,0,0};
    int i0 = ks * 32;
    #pragma unroll 4
    for (int i = i0; i < i0 + 32; i++) {
        float4 w = ((const float4*)(W_out + i * kDin))[q];
        a0 = f4fma(vs[0][i], w, a0);
        a1 = f4fma(vs[1][i], w, a1);
    }
    if (ks) {
        float* rr = red[tid - 32];
        rr[0] = a0.x; rr[1] = a0.y; rr[2] = a0.z; rr[3] = a0.w;
        rr[4] = a1.x; rr[5] = a1.y; rr[6] = a1.z; rr[7] = a1.w;
    }
    __syncthreads();
    if (!ks) {
        #pragma unroll
        for (int p = 0; p < 7; p++) {
            const float* rr = red[p * 32 + tid];
            a0.x += rr[0]; a0.y += rr[1]; a0.z += rr[2]; a0.w += rr[3];
            a1.x += rr[4]; a1.y += rr[5]; a1.z += rr[6]; a1.w += rr[7];
        }
        float4 bv = ((const float4*)b_out)[q];
        a0.x += bv.x; a0.y += bv.y; a0.z += bv.z; a0.w += bv.w;
        a1.x += bv.x; a1.y += bv.y; a1.z += bv.z; a1.w += bv.w;
        ((float4*)(out + (bt0 + 0) * kDin))[q] = a0;
        ((float4*)(out + (bt0 + 1) * kDin))[q] = a1;
    }
}

// ---------------------------------------------------------------------------
extern "C" void kernel_launch(void* const* d_in, const int* in_sizes, int n_in,
                              void* d_out, int out_size, void* d_ws, size_t ws_size,
                              hipStream_t stream) {
    const float* x      = (const float*)d_in[0];
    const float* W_in   = (const float*)d_in[1];
    const float* b_in   = (const float*)d_in[2];
    const float* W_res  = (const float*)d_in[3];
    const float* b_res  = (const float*)d_in[4];
    const float* conv_w = (const float*)d_in[5];
    const float* conv_b = (const float*)d_in[6];
    const float* W_xdt  = (const float*)d_in[7];
    const float* W_dt   = (const float*)d_in[8];
    const float* b_dt   = (const float*)d_in[9];
    const float* W_B    = (const float*)d_in[10];
    const float* W_C    = (const float*)d_in[11];
    const float* A_log  = (const float*)d_in[12];
    const float* Dv     = (const float*)d_in[13];
    const float* W_out  = (const float*)d_in[14];
    const float* b_out  = (const float*)d_in[15];

    // workspace: 6 x 1 MiB slots = 6.00 MiB (<= proven 6.06 budget)
    float* ws    = (float*)d_ws;
    float* slot0 = ws;               // xi -> delta
    float* xres  = ws + 1 * 262144;
    float* slot2 = ws + 2 * 262144;  // wT -> Bmat
    float* u     = ws + 3 * 262144;
    float* yss   = ws + 4 * 262144;
    float* Cmat  = ws + 5 * 262144;

    float* xi    = slot0;
    float* delta = slot0;
    float* wT    = slot2;
    float* Bmat  = slot2;

    pre_kernel<<<768, 256, 0, stream>>>(x, W_in, b_in, W_res, b_res, conv_w,
                                        wT, xi, xres);
    conv_fwd<<<256, 512, 0, stream>>>(xi, wT, conv_b, u);
    proj_bcd<<<512, 256, 0, stream>>>(u, W_xdt, W_dt, b_dt, W_B, W_C,
                                      delta, Bmat, Cmat);
    scan_fused<<<kB * kD, 512, 0, stream>>>(delta, u, Bmat, Cmat, A_log, yss);
    out_proj<<<512, 256, 0, stream>>>(yss, u, Dv, xres, W_out, b_out,
                                      (float*)d_out);
}

// Round 8
// 171.642 us; speedup vs baseline: 3.2650x; 1.0587x over previous
//
#include <hip/hip_runtime.h>
#include <hip/hip_bf16.h>

// Problem constants (B=2, L=512, Din=128, d=N=256, R=16, K=4)
// Established facts: inputs f32, output f32, ws budget <= ~6.1 MiB.
#define kB   2
#define kL   512
#define kBL  1024
#define kDin 128
#define kD   256
#define kN   256
#define kR   16
#define kK   4
#define kS   8     // scan segments (= waves per d)
#define kT   64    // kL / kS

__device__ __forceinline__ float silu_f(float v) { return v / (1.f + __expf(-v)); }
__device__ __forceinline__ float softplus_f(float z) {
    return (z > 20.f) ? z : log1pf(__expf(z));
}
__device__ __forceinline__ float4 f4fma(float s, float4 w, float4 a) {
    a.x += s * w.x; a.y += s * w.y; a.z += s * w.z; a.w += s * w.w; return a;
}

// ---------------------------------------------------------------------------
// K1: blocks [0,256) transpose conv_w [o][ik] -> wT [ik][o];
//     blocks [256,768) proj_in: xi = x@W_in+b_in, xres = silu(x@W_res+b_res).
//     (unchanged from R7)
// ---------------------------------------------------------------------------
__global__ void __launch_bounds__(256) pre_kernel(
        const float* __restrict__ x, const float* __restrict__ W_in,
        const float* __restrict__ b_in, const float* __restrict__ W_res,
        const float* __restrict__ b_res, const float* __restrict__ conv_w,
        float* __restrict__ wT, float* __restrict__ xi, float* __restrict__ xres) {
    __shared__ float tile[32][33];
    __shared__ float xs[2][kDin];
    __shared__ float red[128][9];
    int bid = blockIdx.x, tid = threadIdx.x;
    if (bid < 256) {
        int c0 = (bid & 31) * 32, r0 = (bid >> 5) * 32;
        int tx = tid & 31, ty = tid >> 5;
        #pragma unroll
        for (int j = 0; j < 32; j += 8)
            tile[ty + j][tx] = conv_w[(r0 + ty + j) * 1024 + c0 + tx];
        __syncthreads();
        #pragma unroll
        for (int j = 0; j < 32; j += 8)
            wT[(c0 + ty + j) * 256 + r0 + tx] = tile[tx][ty + j];
        return;
    }
    int bt0 = (bid - 256) * 2;
    xs[tid >> 7][tid & 127] = x[bt0 * kDin + tid];
    __syncthreads();
    int q = tid & 63, m = (tid >> 6) & 1, ks = tid >> 7;
    const float* W = m ? W_res : W_in;
    float4 a0 = {0,0,0,0}, a1 = {0,0,0,0};
    int i0 = ks * 64;
    #pragma unroll 4
    for (int i = i0; i < i0 + 64; i++) {
        float4 w = ((const float4*)(W + i * kD))[q];
        a0 = f4fma(xs[0][i], w, a0);
        a1 = f4fma(xs[1][i], w, a1);
    }
    if (ks) {
        float* rr = red[tid - 128];
        rr[0] = a0.x; rr[1] = a0.y; rr[2] = a0.z; rr[3] = a0.w;
        rr[4] = a1.x; rr[5] = a1.y; rr[6] = a1.z; rr[7] = a1.w;
    }
    __syncthreads();
    if (!ks) {
        const float* rr = red[tid];
        a0.x += rr[0]; a0.y += rr[1]; a0.z += rr[2]; a0.w += rr[3];
        a1.x += rr[4]; a1.y += rr[5]; a1.z += rr[6]; a1.w += rr[7];
        float4 bv = ((const float4*)(m ? b_res : b_in))[q];
        a0.x += bv.x; a0.y += bv.y; a0.z += bv.z; a0.w += bv.w;
        a1.x += bv.x; a1.y += bv.y; a1.z += bv.z; a1.w += bv.w;
        if (m) {
            float4 s0 = {silu_f(a0.x), silu_f(a0.y), silu_f(a0.z), silu_f(a0.w)};
            float4 s1 = {silu_f(a1.x), silu_f(a1.y), silu_f(a1.z), silu_f(a1.w)};
            ((float4*)(xres + (bt0 + 0) * kD))[q] = s0;
            ((float4*)(xres + (bt0 + 1) * kD))[q] = s1;
        } else {
            ((float4*)(xi + (bt0 + 0) * kD))[q] = a0;
            ((float4*)(xi + (bt0 + 1) * kD))[q] = a1;
        }
    }
}

// ---------------------------------------------------------------------------
// K2: u = silu(causal conv1d(xi) + conv_b). (unchanged from R7)
// ---------------------------------------------------------------------------
__global__ void __launch_bounds__(512) conv_fwd(
        const float* __restrict__ xi, const float* __restrict__ wT,
        const float* __restrict__ conv_b, float* __restrict__ u) {
    __shared__ float xs[7][kD];          // rows t0-3 .. t0+3
    __shared__ float red[7][64][17];
    int bid = blockIdx.x, tid = threadIdx.x;
    int b = bid >> 7, t0 = (bid & 127) * 4;
    for (int idx = tid; idx < 7 * kD; idx += 512) {
        int j = idx >> 8, i = idx & 255;
        int t = t0 - 3 + j;
        xs[j][i] = (t >= 0) ? xi[(b * kL + t) * kD + i] : 0.f;
    }
    __syncthreads();
    int q = tid & 63, ks = tid >> 6;
    float4 a[4] = {{0,0,0,0},{0,0,0,0},{0,0,0,0},{0,0,0,0}};
    int ik0 = ks * 128;
    #pragma unroll 4
    for (int ik = ik0; ik < ik0 + 128; ik++) {
        float4 w = ((const float4*)(wT + ik * kD))[q];
        int ii = ik >> 2, k = ik & 3;
        #pragma unroll
        for (int r = 0; r < 4; r++) a[r] = f4fma(xs[k + r][ii], w, a[r]);
    }
    if (ks) {
        float* rr = red[ks - 1][q];
        #pragma unroll
        for (int r = 0; r < 4; r++) {
            rr[4*r+0] = a[r].x; rr[4*r+1] = a[r].y;
            rr[4*r+2] = a[r].z; rr[4*r+3] = a[r].w;
        }
    }
    __syncthreads();
    if (!ks) {
        #pragma unroll
        for (int p = 0; p < 7; p++) {
            const float* rr = red[p][q];
            #pragma unroll
            for (int r = 0; r < 4; r++) {
                a[r].x += rr[4*r+0]; a[r].y += rr[4*r+1];
                a[r].z += rr[4*r+2]; a[r].w += rr[4*r+3];
            }
        }
        float4 cb = ((const float4*)conv_b)[q];
        #pragma unroll
        for (int r = 0; r < 4; r++) {
            float4 v = {silu_f(a[r].x + cb.x), silu_f(a[r].y + cb.y),
                        silu_f(a[r].z + cb.z), silu_f(a[r].w + cb.w)};
            ((float4*)(u + (b * kL + t0 + r) * kD))[q] = v;
        }
    }
}

// ---------------------------------------------------------------------------
// K3: fused xdt + bcd. (unchanged from R7)
// ---------------------------------------------------------------------------
__global__ void __launch_bounds__(256) proj_bcd(
        const float* __restrict__ u, const float* __restrict__ W_xdt,
        const float* __restrict__ W_dt, const float* __restrict__ b_dt,
        const float* __restrict__ W_B, const float* __restrict__ W_C,
        float* __restrict__ delta, float* __restrict__ Bm, float* __restrict__ Cm) {
    __shared__ float us[2][kD];
    __shared__ float tpart[128];
    __shared__ float ts[2][kR];
    __shared__ float red[128][9];
    int bt0 = blockIdx.x * 2, tid = threadIdx.x;
    us[0][tid] = u[(bt0 + 0) * kD + tid];
    us[1][tid] = u[(bt0 + 1) * kD + tid];
    __syncthreads();
    if (tid < 128) {     // t1 partials: r x 16 j x 4 K-quarters
        int r = tid >> 6, j = (tid >> 2) & 15, kq = tid & 3;
        float acc = 0.f;
        #pragma unroll 4
        for (int i = kq * 64; i < kq * 64 + 64; i++)
            acc += us[r][i] * W_xdt[i * kR + j];
        tpart[tid] = acc;
    }
    __syncthreads();
    if (tid < 32) {
        int r = tid >> 4, j = tid & 15;
        int base = r * 64 + j * 4;
        ts[r][j] = tpart[base] + tpart[base+1] + tpart[base+2] + tpart[base+3];
    }
    __syncthreads();
    int q = tid & 63, m = (tid >> 6) & 1, ks = tid >> 7;
    const float* W = m ? W_C : W_B;
    float4 a0 = {0,0,0,0}, a1 = {0,0,0,0};
    int i0 = ks * 128;
    #pragma unroll 4
    for (int i = i0; i < i0 + 128; i++) {
        float4 w = ((const float4*)(W + i * kN))[q];
        a0 = f4fma(us[0][i], w, a0);
        a1 = f4fma(us[1][i], w, a1);
    }
    if (ks) {
        float* rr = red[tid - 128];
        rr[0] = a0.x; rr[1] = a0.y; rr[2] = a0.z; rr[3] = a0.w;
        rr[4] = a1.x; rr[5] = a1.y; rr[6] = a1.z; rr[7] = a1.w;
    }
    __syncthreads();
    if (!ks) {
        const float* rr = red[tid];
        a0.x += rr[0]; a0.y += rr[1]; a0.z += rr[2]; a0.w += rr[3];
        a1.x += rr[4]; a1.y += rr[5]; a1.z += rr[6]; a1.w += rr[7];
        float* O = m ? Cm : Bm;
        ((float4*)(O + (bt0 + 0) * kN))[q] = a0;
        ((float4*)(O + (bt0 + 1) * kN))[q] = a1;
    }
    if (tid < 64) {      // delta: 16-j dot, float4 outs
        float4 d0 = {0,0,0,0}, d1 = {0,0,0,0};
        #pragma unroll
        for (int j = 0; j < kR; j++) {
            float4 w = ((const float4*)(W_dt + j * kD))[tid];
            d0 = f4fma(ts[0][j], w, d0);
            d1 = f4fma(ts[1][j], w, d1);
        }
        float4 bd = ((const float4*)b_dt)[tid];
        float4 o0 = {softplus_f(d0.x + bd.x), softplus_f(d0.y + bd.y),
                     softplus_f(d0.z + bd.z), softplus_f(d0.w + bd.w)};
        float4 o1 = {softplus_f(d1.x + bd.x), softplus_f(d1.y + bd.y),
                     softplus_f(d1.z + bd.z), softplus_f(d1.w + bd.w)};
        ((float4*)(delta + (bt0 + 0) * kD))[tid] = o0;
        ((float4*)(delta + (bt0 + 1) * kD))[tid] = o1;
    }
}

// ---------------------------------------------------------------------------
// K4 v2: segmented selective scan. Block = (b, d-pair), 1024 thr = 16 waves,
//     wave = (s in 0..7, dd in 0..1). The dd=0/1 waves at equal s read
//     IDENTICAL B/C lines and adjacent-d delta/u -> L2 traffic halves.
//     dt/du staged in LDS (broadcast ds_read_b128 in t-loop, no bpermute).
//     t-loop unrolled x4: 16 exps + 4 B/C loads hoisted off the h-chain.
//     y kept at lane t via cndmask -> one store per wave.
// ---------------------------------------------------------------------------
__global__ void __launch_bounds__(1024) scan_fused(
        const float* __restrict__ delta, const float* __restrict__ u,
        const float* __restrict__ Bm, const float* __restrict__ Cm,
        const float* __restrict__ A_log, float* __restrict__ ys) {
    __shared__ float4 hp4[2][kS][64];
    __shared__ float dt_s[16][kT];
    __shared__ float du_s[16][kT];
    __shared__ float dsumS[2][kS];
    int w = threadIdx.x >> 6, lane = threadIdx.x & 63;
    int s = w & 7, dd = w >> 3;
    int b = blockIdx.x >> 7, dp = blockIdx.x & 127;
    int d = dp * 2 + dd;

    float4 al = ((const float4*)(A_log + d * kN))[lane];
    float A0 = -__expf(al.x), A1 = -__expf(al.y);
    float A2 = -__expf(al.z), A3 = -__expf(al.w);

    int gtu = (b * kL + s * kT + lane) * kD + d;
    float my_dt = delta[gtu];
    float my_du = my_dt * u[gtu];

    float dsum = my_dt;
    #pragma unroll
    for (int off = 32; off; off >>= 1) dsum += __shfl_xor(dsum, off, 64);

    dt_s[w][lane] = my_dt;
    du_s[w][lane] = my_du;

    const float4* Bp = (const float4*)(Bm + (b * kL + s * kT) * kN) + lane;
    const float4* Cp = (const float4*)(Cm + (b * kL + s * kT) * kN) + lane;
    __syncthreads();

    // pass 1: segment-local scan from h=0 (reads B only)
    float h0 = 0, h1 = 0, h2 = 0, h3 = 0;
    for (int c = 0; c < kT; c += 4) {
        float4 dt4 = *(const float4*)&dt_s[w][c];
        float4 du4 = *(const float4*)&du_s[w][c];
        float4 Bb[4];
        #pragma unroll
        for (int j = 0; j < 4; j++) Bb[j] = Bp[(c + j) * (kN / 4)];
        float dts[4] = {dt4.x, dt4.y, dt4.z, dt4.w};
        float dus[4] = {du4.x, du4.y, du4.z, du4.w};
        float e[4][4];
        #pragma unroll
        for (int j = 0; j < 4; j++) {
            e[j][0] = __expf(dts[j] * A0);
            e[j][1] = __expf(dts[j] * A1);
            e[j][2] = __expf(dts[j] * A2);
            e[j][3] = __expf(dts[j] * A3);
        }
        #pragma unroll
        for (int j = 0; j < 4; j++) {
            h0 = e[j][0] * h0 + dus[j] * Bb[j].x;
            h1 = e[j][1] * h1 + dus[j] * Bb[j].y;
            h2 = e[j][2] * h2 + dus[j] * Bb[j].z;
            h3 = e[j][3] * h3 + dus[j] * Bb[j].w;
        }
    }
    hp4[dd][s][lane] = make_float4(h0, h1, h2, h3);
    if (lane == 0) dsumS[dd][s] = dsum;
    __syncthreads();

    // combine prior segments (telescoped exp(A * sum dt))
    h0 = h1 = h2 = h3 = 0;
    float P = 0.f;
    for (int j = s - 1; j >= 0; j--) {
        float4 hv = hp4[dd][j][lane];
        h0 += __expf(A0 * P) * hv.x;
        h1 += __expf(A1 * P) * hv.y;
        h2 += __expf(A2 * P) * hv.z;
        h3 += __expf(A3 * P) * hv.w;
        P += dsumS[dd][j];
    }

    // pass 2: rescan with correct h_init; lane t keeps its y; one store/wave
    float my_y = 0.f;
    for (int c = 0; c < kT; c += 4) {
        float4 dt4 = *(const float4*)&dt_s[w][c];
        float4 du4 = *(const float4*)&du_s[w][c];
        float4 Bb[4], Cc[4];
        #pragma unroll
        for (int j = 0; j < 4; j++) {
            Bb[j] = Bp[(c + j) * (kN / 4)];
            Cc[j] = Cp[(c + j) * (kN / 4)];
        }
        float dts[4] = {dt4.x, dt4.y, dt4.z, dt4.w};
        float dus[4] = {du4.x, du4.y, du4.z, du4.w};
        float e[4][4];
        #pragma unroll
        for (int j = 0; j < 4; j++) {
            e[j][0] = __expf(dts[j] * A0);
            e[j][1] = __expf(dts[j] * A1);
            e[j][2] = __expf(dts[j] * A2);
            e[j][3] = __expf(dts[j] * A3);
        }
        #pragma unroll
        for (int j = 0; j < 4; j++) {
            h0 = e[j][0] * h0 + dus[j] * Bb[j].x;
            h1 = e[j][1] * h1 + dus[j] * Bb[j].y;
            h2 = e[j][2] * h2 + dus[j] * Bb[j].z;
            h3 = e[j][3] * h3 + dus[j] * Bb[j].w;
            float y = h0 * Cc[j].x + h1 * Cc[j].y + h2 * Cc[j].z + h3 * Cc[j].w;
            #pragma unroll
            for (int off = 32; off; off >>= 1) y += __shfl_xor(y, off, 64);
            my_y = (lane == c + j) ? y : my_y;
        }
    }
    ys[(b * kL + s * kT + lane) * kD + d] = my_y;
}

// ---------------------------------------------------------------------------
// K5: out = (ys + u*D + xres) @ W_out + b_out -> f32. (unchanged from R7)
// ---------------------------------------------------------------------------
__global__ void __launch_bounds__(256) out_proj(
        const float* __restrict__ ys, const float* __restrict__ u,
        const float* __restrict__ Dv, const float* __restrict__ xres,
        const float* __restrict__ W_out, const float* __restrict__ b_out,
        float* __restrict__ out) {
    __shared__ float vs[2][kD];
    __shared__ float red[224][9];
    int bt0 = blockIdx.x * 2, tid = threadIdx.x;
    for (int idx = tid; idx < 512; idx += 256) {
        int r = idx >> 8, i = idx & 255;
        int g = (bt0 + r) * kD + i;
        vs[r][i] = ys[g] + u[g] * Dv[i] + xres[g];
    }
    __syncthreads();
    int q = tid & 31, ks = tid >> 5;
    float4 a0 = {0,0,0,0}, a1 = {0,0,0,0};
    int i0 = ks * 32;
    #pragma unroll 4
    for (int i = i0; i < i0 + 32; i++) {
        float4 w = ((const float4*)(W_out + i * kDin))[q];
        a0 = f4fma(vs[0][i], w, a0);
        a1 = f4fma(vs[1][i], w, a1);
    }
    if (ks) {
        float* rr = red[tid - 32];
        rr[0] = a0.x; rr[1] = a0.y; rr[2] = a0.z; rr[3] = a0.w;
        rr[4] = a1.x; rr[5] = a1.y; rr[6] = a1.z; rr[7] = a1.w;
    }
    __syncthreads();
    if (!ks) {
        #pragma unroll
        for (int p = 0; p < 7; p++) {
            const float* rr = red[p * 32 + tid];
            a0.x += rr[0]; a0.y += rr[1]; a0.z += rr[2]; a0.w += rr[3];
            a1.x += rr[4]; a1.y += rr[5]; a1.z += rr[6]; a1.w += rr[7];
        }
        float4 bv = ((const float4*)b_out)[q];
        a0.x += bv.x; a0.y += bv.y; a0.z += bv.z; a0.w += bv.w;
        a1.x += bv.x; a1.y += bv.y; a1.z += bv.z; a1.w += bv.w;
        ((float4*)(out + (bt0 + 0) * kDin))[q] = a0;
        ((float4*)(out + (bt0 + 1) * kDin))[q] = a1;
    }
}

// ---------------------------------------------------------------------------
extern "C" void kernel_launch(void* const* d_in, const int* in_sizes, int n_in,
                              void* d_out, int out_size, void* d_ws, size_t ws_size,
                              hipStream_t stream) {
    const float* x      = (const float*)d_in[0];
    const float* W_in   = (const float*)d_in[1];
    const float* b_in   = (const float*)d_in[2];
    const float* W_res  = (const float*)d_in[3];
    const float* b_res  = (const float*)d_in[4];
    const float* conv_w = (const float*)d_in[5];
    const float* conv_b = (const float*)d_in[6];
    const float* W_xdt  = (const float*)d_in[7];
    const float* W_dt   = (const float*)d_in[8];
    const float* b_dt   = (const float*)d_in[9];
    const float* W_B    = (const float*)d_in[10];
    const float* W_C    = (const float*)d_in[11];
    const float* A_log  = (const float*)d_in[12];
    const float* Dv     = (const float*)d_in[13];
    const float* W_out  = (const float*)d_in[14];
    const float* b_out  = (const float*)d_in[15];

    // workspace: 6 x 1 MiB slots = 6.00 MiB (<= proven 6.06 budget)
    float* ws    = (float*)d_ws;
    float* slot0 = ws;               // xi -> delta
    float* xres  = ws + 1 * 262144;
    float* slot2 = ws + 2 * 262144;  // wT -> Bmat
    float* u     = ws + 3 * 262144;
    float* yss   = ws + 4 * 262144;
    float* Cmat  = ws + 5 * 262144;

    float* xi    = slot0;
    float* delta = slot0;
    float* wT    = slot2;
    float* Bmat  = slot2;

    pre_kernel<<<768, 256, 0, stream>>>(x, W_in, b_in, W_res, b_res, conv_w,
                                        wT, xi, xres);
    conv_fwd<<<256, 512, 0, stream>>>(xi, wT, conv_b, u);
    proj_bcd<<<512, 256, 0, stream>>>(u, W_xdt, W_dt, b_dt, W_B, W_C,
                                      delta, Bmat, Cmat);
    scan_fused<<<kB * 128, 1024, 0, stream>>>(delta, u, Bmat, Cmat, A_log, yss);
    out_proj<<<512, 256, 0, stream>>>(yss, u, Dv, xres, W_out, b_out,
                                      (float*)d_out);
}